// Round 1
// baseline (3134.748 us; speedup 1.0000x reference)
//
#include <hip/hip_runtime.h>
#include <hip/hip_fp16.h>
#include <stdint.h>

#define Q_MAX 127.0f
#define EPSQ  1e-5f

typedef int v4i __attribute__((ext_vector_type(4)));

#define BM 128
#define BN 256
#define BK 64
#define NTHR 512

__device__ __forceinline__ int pack4i(int a, int b, int c, int d) {
    return (a & 0xff) | ((b & 0xff) << 8) | ((c & 0xff) << 16) | (d << 24);
}
// reference epilogue: fp16(acc*sm*scw) + fp16(bias), computed in fp16, returned as f32
__device__ __forceinline__ float ep(float v, float b) {
    return __half2float(__hadd(__float2half(v), __float2half(b)));
}

// Single fused kernel: per-row absmax -> int8 quant -> int8 GEMM -> dequant+bias.
// Pure function of (x, w32, scw, bias); no workspace, no cross-kernel state.
__global__ __launch_bounds__(NTHR) void w8a8_one(const float* __restrict__ x,    // f32 (fp16 values), [M,K]
                                                 const int* __restrict__ w32,    // int32 (int8 values), [N,K]
                                                 const float* __restrict__ scw,  // [N]
                                                 const float* __restrict__ bias, // [N] f32 (fp16 values)
                                                 float* __restrict__ out,        // [M,N] f32
                                                 int M, int N, int K) {
    __shared__ __align__(16) int8_t As[BM * BK];
    __shared__ __align__(16) int8_t Bs[BN * BK];
    __shared__ float sS[BM];
    __shared__ float sR[BM];

    const int t  = threadIdx.x;
    const int w  = t >> 6;
    const int l  = t & 63;
    const int wm = w & 1;       // 2 waves along M (64 rows each)
    const int wn = w >> 1;      // 4 waves along N (64 cols each)

    // XCD-chunked, bm-major order: each XCD gets a contiguous run of logical
    // blocks; within a run bm is fixed for nbn consecutive blocks -> the 2MB
    // f32 A-panel stays resident in that XCD's L2 across the run.
    const int nbn  = N / BN;
    const int nblk = (M / BM) * nbn;
    int L = blockIdx.x;
    if ((nblk & 7) == 0) {                 // bijective only when divisible (ERRATA #11 guard)
        const int c = nblk >> 3;
        L = (L & 7) * c + (L >> 3);
    }
    const int bm = (L / nbn) * BM;
    const int bn = (L % nbn) * BN;

    // ---- phase 1: per-row absmax (4 threads/row, interleaved float4) ----
    {
        const int row = t >> 2;
        const int seg = t & 3;
        const float4* p = (const float4*)(x + (size_t)(bm + row) * K) + seg;
        float amax = 0.f;
        for (int j = 0; j < K / 16; ++j) {           // K/16 float4 per thread, stride 4
            float4 v = p[j * 4];
            amax = fmaxf(amax, fmaxf(fmaxf(fabsf(v.x), fabsf(v.y)),
                                     fmaxf(fabsf(v.z), fabsf(v.w))));
        }
        amax = fmaxf(amax, __shfl_xor(amax, 1));
        amax = fmaxf(amax, __shfl_xor(amax, 2));
        if (seg == 0) {
            const float s = fmaxf(amax, EPSQ) / Q_MAX;   // matches reference scale exactly
            sS[row] = s;
            sR[row] = 1.0f / s;
        }
    }
    __syncthreads();

    // ---- staging maps ----
    // A: 4 threads/row, 16 floats each; XOR swizzle: logical chunk q stored at q^((row>>1)&3)
    const int ra  = t >> 2;
    const int sa  = t & 3;
    const float rs = sR[ra];
    const float4* gA = (const float4*)(x + (size_t)(bm + ra) * K);
    int8_t* dA = As + ra * 64 + ((sa ^ ((ra >> 1) & 3)) << 4);

    // B: 2 threads/row, 32 int32 each (nontemporal: streamed, protect L2)
    const int rb  = t >> 1;
    const int hb  = t & 1;
    const int swb = (rb >> 1) & 3;
    const int* gB = w32 + (size_t)(bn + rb) * K + hb * 32;
    int8_t* dB0 = Bs + rb * 64 + ((((hb * 2)    ) ^ swb) << 4);
    int8_t* dB1 = Bs + rb * 64 + ((((hb * 2) + 1) ^ swb) << 4);

    // fragment reads: m/n = lane&15, logical k-chunk q = lane>>4 at physical q^((fr>>1)&3)
    const int fr   = l & 15;
    const int fc   = (l >> 4) ^ ((fr >> 1) & 3);
    const int aoff = (wm * 64 + fr) * 64 + fc * 16;
    const int boff = (wn * 64 + fr) * 64 + fc * 16;

    v4i acc[4][4] = {};

#pragma unroll 1
    for (int kt = 0; kt < K; kt += BK) {
        __syncthreads();
        {   // A-tile: load 16 f32, quantize, pack, one ds_write_b128
            const float4* pa = gA + (kt >> 2) + sa * 4;
            float va[16];
            *(float4*)(va + 0)  = pa[0];
            *(float4*)(va + 4)  = pa[1];
            *(float4*)(va + 8)  = pa[2];
            *(float4*)(va + 12) = pa[3];
            int q[16];
#pragma unroll
            for (int i = 0; i < 16; ++i) q[i] = __float2int_rn(va[i] * rs);
            int pk[4];
#pragma unroll
            for (int c2 = 0; c2 < 4; ++c2)
                pk[c2] = pack4i(q[c2 * 4 + 0], q[c2 * 4 + 1], q[c2 * 4 + 2], q[c2 * 4 + 3]);
            *(int4*)dA = *(const int4*)pk;
        }
        {   // B-tile: load 32 int32 (nt), pack to int8, two ds_write_b128
            const v4i* g4 = (const v4i*)(gB + kt);
            v4i u0 = __builtin_nontemporal_load(g4 + 0);
            v4i u1 = __builtin_nontemporal_load(g4 + 1);
            v4i u2 = __builtin_nontemporal_load(g4 + 2);
            v4i u3 = __builtin_nontemporal_load(g4 + 3);
            v4i u4 = __builtin_nontemporal_load(g4 + 4);
            v4i u5 = __builtin_nontemporal_load(g4 + 5);
            v4i u6 = __builtin_nontemporal_load(g4 + 6);
            v4i u7 = __builtin_nontemporal_load(g4 + 7);
            int p0[4] = { pack4i(u0[0],u0[1],u0[2],u0[3]), pack4i(u1[0],u1[1],u1[2],u1[3]),
                          pack4i(u2[0],u2[1],u2[2],u2[3]), pack4i(u3[0],u3[1],u3[2],u3[3]) };
            int p1[4] = { pack4i(u4[0],u4[1],u4[2],u4[3]), pack4i(u5[0],u5[1],u5[2],u5[3]),
                          pack4i(u6[0],u6[1],u6[2],u6[3]), pack4i(u7[0],u7[1],u7[2],u7[3]) };
            *(int4*)dB0 = *(const int4*)p0;
            *(int4*)dB1 = *(const int4*)p1;
        }
        __syncthreads();

        v4i a[4], b[4];
#pragma unroll
        for (int i = 0; i < 4; ++i) a[i] = *(const v4i*)(As + aoff + i * 16 * 64);
#pragma unroll
        for (int j = 0; j < 4; ++j) b[j] = *(const v4i*)(Bs + boff + j * 16 * 64);
#pragma unroll
        for (int i = 0; i < 4; ++i)
#pragma unroll
            for (int j = 0; j < 4; ++j)
                acc[i][j] = __builtin_amdgcn_mfma_i32_16x16x64_i8(a[i], b[j], acc[i][j], 0, 0, 0);
    }

    // epilogue: C/D layout col=lane&15, row=(lane>>4)*4+reg; nt stores (streamed output)
    const int colb = bn + wn * 64 + fr;
#pragma unroll
    for (int i = 0; i < 4; ++i) {
        const int r0 = wm * 64 + i * 16 + (l >> 4) * 4;
#pragma unroll
        for (int r = 0; r < 4; ++r) {
            const float sm = sS[r0 + r];
            float* orow = out + (size_t)(bm + r0 + r) * N;
#pragma unroll
            for (int j = 0; j < 4; ++j) {
                const int n = colb + j * 16;
                __builtin_nontemporal_store(ep((float)acc[i][j][r] * sm * scw[n], bias[n]), orow + n);
            }
        }
    }
}

extern "C" void kernel_launch(void* const* d_in, const int* in_sizes, int n_in,
                              void* d_out, int out_size, void* d_ws, size_t ws_size,
                              hipStream_t stream) {
    const float* x    = (const float*)d_in[0];   // f32 (fp16 reference values)
    const int*   wgt  = (const int*)d_in[1];     // int32 (int8 values)
    const float* scw  = (const float*)d_in[2];
    const float* bias = (const float*)d_in[3];   // f32 (fp16 reference values)
    float* out = (float*)d_out;                  // f32 output

    const int N = in_sizes[2];                   // 11008
    const int K = in_sizes[1] / N;               // 4096
    const int M = in_sizes[0] / K;               // 4096

    (void)d_ws; (void)ws_size;                   // deliberately unused: pure function of inputs
    const int nblk = (M / BM) * (N / BN);        // 32 * 43 = 1376
    w8a8_one<<<dim3(nblk), NTHR, 0, stream>>>(x, wgt, scw, bias, out, M, N, K);
}

// Round 3
// 1859.492 us; speedup vs baseline: 1.6858x; 1.6858x over previous
//
#include <hip/hip_runtime.h>
#include <hip/hip_fp16.h>
#include <stdint.h>

#define Q_MAX 127.0f
#define EPSQ  1e-5f

typedef int v4i __attribute__((ext_vector_type(4)));

#define BM 128
#define BN 256
#define BK 64
#define NTHR 512

__device__ __forceinline__ int pack4i(int a, int b, int c, int d) {
    return (a & 0xff) | ((b & 0xff) << 8) | ((c & 0xff) << 16) | (d << 24);
}
// reference epilogue: fp16(acc*sm*scw) + fp16(bias), computed in fp16, returned as f32
__device__ __forceinline__ float ep(float v, float b) {
    return __half2float(__hadd(__float2half(v), __float2half(b)));
}

// Single fused kernel: per-row absmax -> int8 quant -> int8 GEMM -> dequant+bias.
// Pure function of (x, w32, scw, bias); no workspace, no cross-kernel state.
// v2: B loads cacheable (weights are L3-resident, 180MB < 256MB), nt only on the
//     output stream; double-buffered LDS with early-issued global loads so the
//     L2/L3 fetch latency hides under the MFMA phase.
__global__ __launch_bounds__(NTHR) void w8a8_one(const float* __restrict__ x,    // f32 (fp16 values), [M,K]
                                                 const int* __restrict__ w32,    // int32 (int8 values), [N,K]
                                                 const float* __restrict__ scw,  // [N]
                                                 const float* __restrict__ bias, // [N] f32 (fp16 values)
                                                 float* __restrict__ out,        // [M,N] f32
                                                 int M, int N, int K) {
    __shared__ __align__(16) int8_t As[2][BM * BK];
    __shared__ __align__(16) int8_t Bs[2][BN * BK];
    __shared__ float sS[BM];
    __shared__ float sR[BM];

    const int t  = threadIdx.x;
    const int w  = t >> 6;
    const int l  = t & 63;
    const int wm = w & 1;       // 2 waves along M (64 rows each)
    const int wn = w >> 1;      // 4 waves along N (64 cols each)

    // XCD-chunked, bm-major order: 1376 blocks = 8 XCDs x 172; 172 = 4 bm-panels
    // x 43 bn-blocks, so each XCD keeps its 2MB f32 A-panel resident in L2 while
    // streaming B through L2 from the (fully resident) L3 copy of the weights.
    const int nbn  = N / BN;
    const int nblk = (M / BM) * nbn;
    int L = blockIdx.x;
    if ((nblk & 7) == 0) {                 // bijective only when divisible (ERRATA #11 guard)
        const int c = nblk >> 3;
        L = (L & 7) * c + (L >> 3);
    }
    const int bm = (L / nbn) * BM;
    const int bn = (L % nbn) * BN;

    // ---- phase 1: per-row absmax (4 threads/row, interleaved float4) ----
    {
        const int row = t >> 2;
        const int seg = t & 3;
        const float4* p = (const float4*)(x + (size_t)(bm + row) * K) + seg;
        float amax = 0.f;
        for (int j = 0; j < K / 16; ++j) {           // K/16 float4 per thread, stride 4
            float4 v = p[j * 4];
            amax = fmaxf(amax, fmaxf(fmaxf(fabsf(v.x), fabsf(v.y)),
                                     fmaxf(fabsf(v.z), fabsf(v.w))));
        }
        amax = fmaxf(amax, __shfl_xor(amax, 1));
        amax = fmaxf(amax, __shfl_xor(amax, 2));
        if (seg == 0) {
            const float s = fmaxf(amax, EPSQ) / Q_MAX;   // matches reference scale exactly
            sS[row] = s;
            sR[row] = 1.0f / s;
        }
    }
    __syncthreads();

    // ---- staging maps ----
    // A: 4 threads/row, 16 floats each; XOR swizzle: logical chunk q stored at q^((row>>1)&3)
    const int ra  = t >> 2;
    const int sa  = t & 3;
    const float rs = sR[ra];
    const float4* gA = (const float4*)(x + (size_t)(bm + ra) * K) + sa * 4;
    const int offA = ra * 64 + ((sa ^ ((ra >> 1) & 3)) << 4);

    // B: 2 threads/row, 32 int32 each (cacheable: L3 holds the whole weight matrix)
    const int rb  = t >> 1;
    const int hb  = t & 1;
    const int swb = (rb >> 1) & 3;
    const int* gB = w32 + (size_t)(bn + rb) * K + hb * 32;
    const int offB0 = rb * 64 + ((((hb * 2)    ) ^ swb) << 4);
    const int offB1 = rb * 64 + ((((hb * 2) + 1) ^ swb) << 4);

    // fragment reads: m/n = lane&15, logical k-chunk q = lane>>4 at physical q^((fr>>1)&3)
    const int fr   = l & 15;
    const int fc   = (l >> 4) ^ ((fr >> 1) & 3);
    const int aoff = (wm * 64 + fr) * 64 + fc * 16;
    const int boff = (wn * 64 + fr) * 64 + fc * 16;

    v4i acc[4][4] = {};

    float4 rA[4];   // in-flight A tile (16 f32)
    v4i    rB[8];   // in-flight B tile (32 i32)

    auto load_tile = [&](int kt) {
#pragma unroll
        for (int i = 0; i < 4; ++i) rA[i] = gA[(kt >> 2) + i];
        const v4i* g4 = (const v4i*)(gB + kt);
#pragma unroll
        for (int i = 0; i < 8; ++i) rB[i] = g4[i];
    };
    auto pack_write = [&](int buf) {
        const float* vals = (const float*)rA;
        int q[16];
#pragma unroll
        for (int i = 0; i < 16; ++i) q[i] = __float2int_rn(vals[i] * rs);
        int pk[4];
#pragma unroll
        for (int c2 = 0; c2 < 4; ++c2)
            pk[c2] = pack4i(q[c2 * 4 + 0], q[c2 * 4 + 1], q[c2 * 4 + 2], q[c2 * 4 + 3]);
        *(int4*)(As[buf] + offA) = *(const int4*)pk;
        int p0[4] = { pack4i(rB[0][0],rB[0][1],rB[0][2],rB[0][3]),
                      pack4i(rB[1][0],rB[1][1],rB[1][2],rB[1][3]),
                      pack4i(rB[2][0],rB[2][1],rB[2][2],rB[2][3]),
                      pack4i(rB[3][0],rB[3][1],rB[3][2],rB[3][3]) };
        int p1[4] = { pack4i(rB[4][0],rB[4][1],rB[4][2],rB[4][3]),
                      pack4i(rB[5][0],rB[5][1],rB[5][2],rB[5][3]),
                      pack4i(rB[6][0],rB[6][1],rB[6][2],rB[6][3]),
                      pack4i(rB[7][0],rB[7][1],rB[7][2],rB[7][3]) };
        *(int4*)(Bs[buf] + offB0) = *(const int4*)p0;
        *(int4*)(Bs[buf] + offB1) = *(const int4*)p1;
    };

    // prologue: stage tile 0 into buf 0
    load_tile(0);
    pack_write(0);

    int cur = 0;
#pragma unroll 1
    for (int kt = 0; kt < K; kt += BK) {
        __syncthreads();                       // buf[cur] writes visible to all waves
        const bool more = (kt + BK) < K;
        if (more) load_tile(kt + BK);          // issue next tile's loads; in flight under MFMA

        const int8_t* Ab = As[cur];
        const int8_t* Bb = Bs[cur];
        v4i a[4], b[4];
#pragma unroll
        for (int i = 0; i < 4; ++i) a[i] = *(const v4i*)(Ab + aoff + i * 16 * 64);
#pragma unroll
        for (int j = 0; j < 4; ++j) b[j] = *(const v4i*)(Bb + boff + j * 16 * 64);
#pragma unroll
        for (int i = 0; i < 4; ++i)
#pragma unroll
            for (int j = 0; j < 4; ++j)
                acc[i][j] = __builtin_amdgcn_mfma_i32_16x16x64_i8(a[i], b[j], acc[i][j], 0, 0, 0);

        __syncthreads();                       // all waves done reading buf[cur]
        if (more) pack_write(cur ^ 1);         // drain loads (vmcnt), quantize, stage next buf
        cur ^= 1;
    }

    // epilogue: C/D layout col=lane&15, row=(lane>>4)*4+reg; nt stores (streamed output,
    // keep it out of L3 so the weight matrix stays resident)
    const int colb = bn + wn * 64 + fr;
#pragma unroll
    for (int i = 0; i < 4; ++i) {
        const int r0 = wm * 64 + i * 16 + (l >> 4) * 4;
#pragma unroll
        for (int r = 0; r < 4; ++r) {
            const float sm = sS[r0 + r];
            float* orow = out + (size_t)(bm + r0 + r) * N;
#pragma unroll
            for (int j = 0; j < 4; ++j) {
                const int n = colb + j * 16;
                __builtin_nontemporal_store(ep((float)acc[i][j][r] * sm * scw[n], bias[n]), orow + n);
            }
        }
    }
}

extern "C" void kernel_launch(void* const* d_in, const int* in_sizes, int n_in,
                              void* d_out, int out_size, void* d_ws, size_t ws_size,
                              hipStream_t stream) {
    const float* x    = (const float*)d_in[0];   // f32 (fp16 reference values)
    const int*   wgt  = (const int*)d_in[1];     // int32 (int8 values)
    const float* scw  = (const float*)d_in[2];
    const float* bias = (const float*)d_in[3];   // f32 (fp16 reference values)
    float* out = (float*)d_out;                  // f32 output

    const int N = in_sizes[2];                   // 11008
    const int K = in_sizes[1] / N;               // 4096
    const int M = in_sizes[0] / K;               // 4096

    (void)d_ws; (void)ws_size;                   // deliberately unused: pure function of inputs
    const int nblk = (M / BM) * (N / BN);        // 32 * 43 = 1376
    w8a8_one<<<dim3(nblk), NTHR, 0, stream>>>(x, wgt, scw, bias, out, M, N, K);
}

// Round 4
// 753.021 us; speedup vs baseline: 4.1629x; 2.4694x over previous
//
#include <hip/hip_runtime.h>
#include <hip/hip_fp16.h>
#include <hip/hip_cooperative_groups.h>
#include <stdint.h>

namespace cg = cooperative_groups;

#define Q_MAX 127.0f
#define EPSQ  1e-5f

typedef int   v4i __attribute__((ext_vector_type(4)));
typedef float v4f __attribute__((ext_vector_type(4)));

__device__ __forceinline__ int pack4i(int a, int b, int c, int d) {
    return (a & 0xff) | ((b & 0xff) << 8) | ((c & 0xff) << 16) | (d << 24);
}
// reference epilogue: fp16(acc*sm*scw) + fp16(bias), computed in fp16, returned as f32
__device__ __forceinline__ float ep(float v, float b) {
    return __half2float(__hadd(__float2half(v), __float2half(b)));
}
__device__ __forceinline__ void async16(const void* g, const void* l) {
    __builtin_amdgcn_global_load_lds((const __attribute__((address_space(1))) uint32_t*)g,
                                     (__attribute__((address_space(3))) uint32_t*)l,
                                     16, 0, 0);
}

// ================= cooperative single-dispatch fast path =========================
// Phase A: pack w32->w8 (45MB, L3-resident) + quant x->xq once.  grid.sync().
// Phase B: int8 GEMM from the packed ws buffers (async16 staging, m97 structure).
// Pure per call: every ws byte read in phase B is written in phase A of the SAME call.
#define BMc 128
#define BNc 128
#define BKc 64
#define CTHR 256
#define CGRID 688

__global__ __launch_bounds__(CTHR, 3) void w8a8_coop(const float* __restrict__ x,
                                                     const int* __restrict__ w32,
                                                     const float* __restrict__ scw,
                                                     const float* __restrict__ bias,
                                                     float* __restrict__ out,
                                                     int8_t* __restrict__ w8,
                                                     int8_t* __restrict__ xq,
                                                     float* __restrict__ scales,
                                                     int M, int N, int K) {
    __shared__ __align__(16) int8_t As[BMc * BKc];   // 8 KB
    __shared__ __align__(16) int8_t Bs[BNc * BKc];   // 8 KB

    const int t   = threadIdx.x;
    const int bid = blockIdx.x;

    // ---- phase A1: w32 -> w8, fully coalesced (each thread: int4 in -> int word out)
    {
        const int T   = CGRID * CTHR;
        const int tg  = bid * CTHR + t;
        const v4i* src = (const v4i*)w32;
        int* dst = (int*)w8;
        const int tot = (N * K) >> 2;           // #int4 chunks == #output words
#pragma unroll 4
        for (int h = tg; h < tot; h += T) {
            v4i u = __builtin_nontemporal_load(src + h);   // single-use stream: keep out of caches
            dst[h] = pack4i(u[0], u[1], u[2], u[3]);
        }
    }
    // ---- phase A2: per-row absmax + quantize x -> xq (8 rows/block, 32 lanes/row)
    {
        const int row = bid * 8 + (t >> 5);
        const int l2  = t & 31;
        if (bid < 512 && row < M) {
            const v4f* p = (const v4f*)(x + (size_t)row * K);
            float amax = 0.f;
            for (int i = 0; i < K / 128; ++i) {
                v4f v = p[l2 + 32 * i];
                amax = fmaxf(amax, fmaxf(fmaxf(fabsf(v[0]), fabsf(v[1])),
                                         fmaxf(fabsf(v[2]), fabsf(v[3]))));
            }
#pragma unroll
            for (int off = 16; off >= 1; off >>= 1) amax = fmaxf(amax, __shfl_xor(amax, off));
            const float s  = fmaxf(amax, EPSQ) / Q_MAX;    // matches reference scale exactly
            const float rs = 1.0f / s;
            if (l2 == 0) scales[row] = s;
            int* q4 = (int*)(xq + (size_t)row * K);
            for (int i = 0; i < K / 128; ++i) {
                v4f v = p[l2 + 32 * i];                    // second pass: L2/L3-hot
                q4[l2 + 32 * i] = pack4i(__float2int_rn(v[0] * rs), __float2int_rn(v[1] * rs),
                                         __float2int_rn(v[2] * rs), __float2int_rn(v[3] * rs));
            }
        }
    }
    __threadfence();          // device-scope release: flush dirty L2 lines before cross-XCD reads
    cg::this_grid().sync();

    // ---- phase B: GEMM, 4 grid-strided 128x128 tiles per block ----
    const int w  = t >> 6;
    const int l  = t & 63;
    const int wm = w & 1;
    const int wn = w >> 1;

    // staging map (verified layout): wave w stages rows w*32+{0..15} and +16; XOR k-chunk swizzle
    const int rA0 = w * 32 + (l >> 2);
    const int rA1 = rA0 + 16;
    const int cq0 = (l & 3) ^ ((rA0 >> 1) & 3);
    const int cq1 = (l & 3) ^ ((rA1 >> 1) & 3);
    int8_t* lA0 = As + w * 2048;            // wave-uniform base (HW adds lane*16)
    int8_t* lA1 = As + w * 2048 + 1024;
    int8_t* lB0 = Bs + w * 2048;
    int8_t* lB1 = Bs + w * 2048 + 1024;

    // fragment reads: m/n = lane&15, logical k-chunk q = lane>>4 at physical q^((fr>>1)&3)
    const int fr   = l & 15;
    const int fc   = (l >> 4) ^ ((fr >> 1) & 3);
    const int aoff = (wm * 64 + fr) * 64 + fc * 16;
    const int boff = (wn * 64 + fr) * 64 + fc * 16;

    const int nbn  = N / BNc;               // 86
    const int nblk = (M / BMc) * nbn;       // 2752 = 8 * 344

    for (int sidx = bid; sidx < nblk; sidx += CGRID) {
        int L = sidx;
        if ((nblk & 7) == 0) L = (sidx & 7) * (nblk >> 3) + (sidx >> 3);  // XCD-chunked, bijective
        const int bm = (L / nbn) * BMc;
        const int bn = (L % nbn) * BNc;

        const int8_t* gA0 = xq + (size_t)(bm + rA0) * K + cq0 * 16;
        const int8_t* gA1 = xq + (size_t)(bm + rA1) * K + cq1 * 16;
        const int8_t* gB0 = w8 + (size_t)(bn + rA0) * K + cq0 * 16;
        const int8_t* gB1 = w8 + (size_t)(bn + rA1) * K + cq1 * 16;

        v4i acc[4][4] = {};

        for (int kt = 0; kt < K; kt += BKc) {
            __syncthreads();                       // prior tile-step LDS reads complete
            async16(gA0 + kt, lA0);
            async16(gA1 + kt, lA1);
            async16(gB0 + kt, lB0);
            async16(gB1 + kt, lB1);
            __syncthreads();                       // drains vmcnt: staged data visible

            v4i a[4], b[4];
#pragma unroll
            for (int i = 0; i < 4; ++i) a[i] = *(const v4i*)(As + aoff + i * 16 * 64);
#pragma unroll
            for (int j = 0; j < 4; ++j) b[j] = *(const v4i*)(Bs + boff + j * 16 * 64);
#pragma unroll
            for (int i = 0; i < 4; ++i)
#pragma unroll
                for (int j = 0; j < 4; ++j)
                    acc[i][j] = __builtin_amdgcn_mfma_i32_16x16x64_i8(a[i], b[j], acc[i][j], 0, 0, 0);
        }

        // epilogue: C/D layout col=lane&15, row=(lane>>4)*4+reg; nt stores (write-once stream)
        const int colb = bn + wn * 64 + fr;
#pragma unroll
        for (int i = 0; i < 4; ++i) {
            const int m0 = bm + wm * 64 + i * 16 + (l >> 4) * 4;
#pragma unroll
            for (int r = 0; r < 4; ++r) {
                const float sm = scales[m0 + r];
                float* orow = out + (size_t)(m0 + r) * N;
#pragma unroll
                for (int j = 0; j < 4; ++j) {
                    const int n = colb + j * 16;
                    __builtin_nontemporal_store(ep((float)acc[i][j][r] * sm * scw[n], bias[n]), orow + n);
                }
            }
        }
    }
}

// ================= v2 fallback: self-contained, zero-workspace (proven pass) ======
#define BM 128
#define BN 256
#define BK 64
#define NTHR 512

__global__ __launch_bounds__(NTHR) void w8a8_one(const float* __restrict__ x,
                                                 const int* __restrict__ w32,
                                                 const float* __restrict__ scw,
                                                 const float* __restrict__ bias,
                                                 float* __restrict__ out,
                                                 int M, int N, int K) {
    __shared__ __align__(16) int8_t As[2][BM * BK];
    __shared__ __align__(16) int8_t Bs[2][BN * BK];
    __shared__ float sS[BM];
    __shared__ float sR[BM];

    const int t  = threadIdx.x;
    const int w  = t >> 6;
    const int l  = t & 63;
    const int wm = w & 1;
    const int wn = w >> 1;

    const int nbn  = N / BN;
    const int nblk = (M / BM) * nbn;
    int L = blockIdx.x;
    if ((nblk & 7) == 0) {
        const int c = nblk >> 3;
        L = (L & 7) * c + (L >> 3);
    }
    const int bm = (L / nbn) * BM;
    const int bn = (L % nbn) * BN;

    {
        const int row = t >> 2;
        const int seg = t & 3;
        const float4* p = (const float4*)(x + (size_t)(bm + row) * K) + seg;
        float amax = 0.f;
        for (int j = 0; j < K / 16; ++j) {
            float4 v = p[j * 4];
            amax = fmaxf(amax, fmaxf(fmaxf(fabsf(v.x), fabsf(v.y)),
                                     fmaxf(fabsf(v.z), fabsf(v.w))));
        }
        amax = fmaxf(amax, __shfl_xor(amax, 1));
        amax = fmaxf(amax, __shfl_xor(amax, 2));
        if (seg == 0) {
            const float s = fmaxf(amax, EPSQ) / Q_MAX;
            sS[row] = s;
            sR[row] = 1.0f / s;
        }
    }
    __syncthreads();

    const int ra  = t >> 2;
    const int sa  = t & 3;
    const float rs = sR[ra];
    const float4* gA = (const float4*)(x + (size_t)(bm + ra) * K) + sa * 4;
    const int offA = ra * 64 + ((sa ^ ((ra >> 1) & 3)) << 4);

    const int rb  = t >> 1;
    const int hb  = t & 1;
    const int swb = (rb >> 1) & 3;
    const int* gB = w32 + (size_t)(bn + rb) * K + hb * 32;
    const int offB0 = rb * 64 + ((((hb * 2)    ) ^ swb) << 4);
    const int offB1 = rb * 64 + ((((hb * 2) + 1) ^ swb) << 4);

    const int fr   = l & 15;
    const int fc   = (l >> 4) ^ ((fr >> 1) & 3);
    const int aoff = (wm * 64 + fr) * 64 + fc * 16;
    const int boff = (wn * 64 + fr) * 64 + fc * 16;

    v4i acc[4][4] = {};
    float4 rA[4];
    v4i    rB[8];

    auto load_tile = [&](int kt) {
#pragma unroll
        for (int i = 0; i < 4; ++i) rA[i] = gA[(kt >> 2) + i];
        const v4i* g4 = (const v4i*)(gB + kt);
#pragma unroll
        for (int i = 0; i < 8; ++i) rB[i] = g4[i];
    };
    auto pack_write = [&](int buf) {
        const float* vals = (const float*)rA;
        int q[16];
#pragma unroll
        for (int i = 0; i < 16; ++i) q[i] = __float2int_rn(vals[i] * rs);
        int pk[4];
#pragma unroll
        for (int c2 = 0; c2 < 4; ++c2)
            pk[c2] = pack4i(q[c2 * 4 + 0], q[c2 * 4 + 1], q[c2 * 4 + 2], q[c2 * 4 + 3]);
        *(int4*)(As[buf] + offA) = *(const int4*)pk;
        int p0[4] = { pack4i(rB[0][0],rB[0][1],rB[0][2],rB[0][3]),
                      pack4i(rB[1][0],rB[1][1],rB[1][2],rB[1][3]),
                      pack4i(rB[2][0],rB[2][1],rB[2][2],rB[2][3]),
                      pack4i(rB[3][0],rB[3][1],rB[3][2],rB[3][3]) };
        int p1[4] = { pack4i(rB[4][0],rB[4][1],rB[4][2],rB[4][3]),
                      pack4i(rB[5][0],rB[5][1],rB[5][2],rB[5][3]),
                      pack4i(rB[6][0],rB[6][1],rB[6][2],rB[6][3]),
                      pack4i(rB[7][0],rB[7][1],rB[7][2],rB[7][3]) };
        *(int4*)(Bs[buf] + offB0) = *(const int4*)p0;
        *(int4*)(Bs[buf] + offB1) = *(const int4*)p1;
    };

    load_tile(0);
    pack_write(0);

    int cur = 0;
#pragma unroll 1
    for (int kt = 0; kt < K; kt += BK) {
        __syncthreads();
        const bool more = (kt + BK) < K;
        if (more) load_tile(kt + BK);

        const int8_t* Ab = As[cur];
        const int8_t* Bb = Bs[cur];
        v4i a[4], b[4];
#pragma unroll
        for (int i = 0; i < 4; ++i) a[i] = *(const v4i*)(Ab + aoff + i * 16 * 64);
#pragma unroll
        for (int j = 0; j < 4; ++j) b[j] = *(const v4i*)(Bb + boff + j * 16 * 64);
#pragma unroll
        for (int i = 0; i < 4; ++i)
#pragma unroll
            for (int j = 0; j < 4; ++j)
                acc[i][j] = __builtin_amdgcn_mfma_i32_16x16x64_i8(a[i], b[j], acc[i][j], 0, 0, 0);

        __syncthreads();
        if (more) pack_write(cur ^ 1);
        cur ^= 1;
    }

    const int colb = bn + wn * 64 + fr;
#pragma unroll
    for (int i = 0; i < 4; ++i) {
        const int r0 = wm * 64 + i * 16 + (l >> 4) * 4;
#pragma unroll
        for (int r = 0; r < 4; ++r) {
            const float sm = sS[r0 + r];
            float* orow = out + (size_t)(bm + r0 + r) * N;
#pragma unroll
            for (int j = 0; j < 4; ++j) {
                const int n = colb + j * 16;
                __builtin_nontemporal_store(ep((float)acc[i][j][r] * sm * scw[n], bias[n]), orow + n);
            }
        }
    }
}

extern "C" void kernel_launch(void* const* d_in, const int* in_sizes, int n_in,
                              void* d_out, int out_size, void* d_ws, size_t ws_size,
                              hipStream_t stream) {
    const float* x    = (const float*)d_in[0];   // f32 (fp16 reference values)
    const int*   wgt  = (const int*)d_in[1];     // int32 (int8 values)
    const float* scw  = (const float*)d_in[2];
    const float* bias = (const float*)d_in[3];   // f32 (fp16 reference values)
    float* out = (float*)d_out;                  // f32 output

    int N = in_sizes[2];                         // 11008
    int K = in_sizes[1] / N;                     // 4096
    int M = in_sizes[0] / K;                     // 4096

    const size_t need = (size_t)N * K + (size_t)M * K + (size_t)M * 4;
    bool done = false;
    if (ws_size >= need && (M % BMc) == 0 && (N % BNc) == 0 && (K % 128) == 0) {
        int8_t* w8     = (int8_t*)d_ws;
        int8_t* xq     = w8 + (size_t)N * K;
        float*  scales = (float*)(xq + (size_t)M * K);
        void* args[] = { (void*)&x, (void*)&wgt, (void*)&scw, (void*)&bias, (void*)&out,
                         (void*)&w8, (void*)&xq, (void*)&scales,
                         (void*)&M, (void*)&N, (void*)&K };
        hipError_t err = hipLaunchCooperativeKernel((const void*)w8a8_coop,
                                                    dim3(CGRID), dim3(CTHR),
                                                    args, 0, stream);
        done = (err == hipSuccess);
    }
    if (!done) {
        const int nblk = (M / BM) * (N / BN);    // 1376
        w8a8_one<<<dim3(nblk), NTHR, 0, stream>>>(x, wgt, scw, bias, out, M, N, K);
    }
}